// Round 7
// baseline (815.274 us; speedup 1.0000x reference)
//
#include <hip/hip_runtime.h>
#include <hip/hip_fp16.h>

#define D 64

__device__ __forceinline__ unsigned h2_as_u(__half2 h) { return *reinterpret_cast<unsigned*>(&h); }
__device__ __forceinline__ __half2 u_as_h2(unsigned u) { return *reinterpret_cast<__half2*>(&u); }

// ---------------- layer-0 init: embs[node][0][:] = concat(user_emb, item_emb) ----
// Also emits the fp16 gather copy (xh) when enabled.
__global__ void init_emb_kernel(const float4* __restrict__ ue, const float4* __restrict__ ie,
                                float4* __restrict__ embs, __half* __restrict__ xh,
                                int n_users, int n) {
    int idx  = blockIdx.x * blockDim.x + threadIdx.x;     // over n*16 float4s
    int node = idx >> 4, q = idx & 15;
    if (node >= n) return;
    float4 v = (node < n_users) ? ue[node * 16 + q] : ie[(node - n_users) * 16 + q];
    embs[(size_t)node * 64 + q] = v;                      // node stride = 256 floats = 64 float4
    if (xh) {
        uint2 o;
        o.x = h2_as_u(__floats2half2_rn(v.x, v.y));
        o.y = h2_as_u(__floats2half2_rn(v.z, v.w));
        ((uint2*)(xh + (size_t)node * 64))[q] = o;        // 128B fp16 row
    }
}

// ================= direct atomic CSR build (1 scattered pass) ====================
// hist: per-row edge counts via global atomics (counts array is L2-resident 600KB)
__global__ void hist_kernel(const int* __restrict__ row, int* __restrict__ counts, int m) {
    int i = blockIdx.x * blockDim.x + threadIdx.x;
    if (i < m) atomicAdd(&counts[row[i]], 1);
}

// blocksum: per-256-chunk sums of counts
__global__ void blocksum_kernel(const int* __restrict__ counts, int* __restrict__ bsum, int n) {
    __shared__ int s[256];
    int t = threadIdx.x;
    int i = blockIdx.x * 256 + t;
    s[t] = (i < n) ? counts[i] : 0;
    __syncthreads();
    for (int d = 128; d > 0; d >>= 1) {
        if (t < d) s[t] += s[t + d];
        __syncthreads();
    }
    if (t == 0) bsum[blockIdx.x] = s[0];
}

// scanb: single-block exclusive scan of block sums (nb <= 1024)
__global__ void __launch_bounds__(1024) scanb_kernel(const int* __restrict__ bsum,
                                                     int* __restrict__ boff, int nb) {
    __shared__ int s[1024];
    int t = threadIdx.x;
    int v = (t < nb) ? bsum[t] : 0;
    s[t] = v;
    for (int d = 1; d < 1024; d <<= 1) {
        __syncthreads();
        int add = (t >= d) ? s[t - d] : 0;
        __syncthreads();
        s[t] += add;
    }
    __syncthreads();
    if (t < nb) boff[t] = s[t] - v;
}

// final: per-chunk exclusive scan + block offset -> offs & cursors
__global__ void final_kernel(int* __restrict__ offs, int* __restrict__ cursors,
                             const int* __restrict__ boff, int n, int total) {
    __shared__ int s[256];
    int t = threadIdx.x;
    int i = blockIdx.x * 256 + t;
    int v = (i < n) ? offs[i] : 0;
    s[t] = v;
    for (int d = 1; d < 256; d <<= 1) {
        __syncthreads();
        int add = (t >= d) ? s[t - d] : 0;
        __syncthreads();
        s[t] += add;
    }
    __syncthreads();
    int excl = s[t] - v + boff[blockIdx.x];
    if (i < n) { offs[i] = excl; cursors[i] = excl; }
    if (i == 0) offs[n] = total;
}

// scatter: one atomic cursor bump + one 8B write per edge (the single scattered pass)
__global__ void scatter_kernel(const int* __restrict__ row, const int* __restrict__ col,
                               const float* __restrict__ val, int* __restrict__ cursors,
                               int2* __restrict__ edges, int m) {
    int i = blockIdx.x * blockDim.x + threadIdx.x;
    if (i >= m) return;
    int r   = row[i];
    int pos = atomicAdd(&cursors[r], 1);
    edges[pos] = make_int2(col[i], __float_as_int(val[i]));
}

// ---------------- fp16-gather SpMM: one wave per row, 4 edges in flight ----------
// Gathers from the fp16 copy (halves gather bytes + x footprint for L2),
// accumulates fp32, writes y fp32 (exact output) + yh fp16 (next layer's source).
__global__ void __launch_bounds__(256) spmm_h_kernel(const int* __restrict__ offs,
                                                     const int2* __restrict__ edges,
                                                     const __half* __restrict__ xh,
                                                     float* __restrict__ y,
                                                     __half* __restrict__ yh, int n) {
    int wid  = (int)((blockIdx.x * (size_t)blockDim.x + threadIdx.x) >> 6);
    if (wid >= n) return;
    int lane = threadIdx.x & 63;
    int eg   = lane >> 4;      // which of 4 concurrent edges
    int c    = lane & 15;      // 4-dim chunk within the 64-dim row
    int beg = offs[wid], end = offs[wid + 1];
    float4 acc = make_float4(0.f, 0.f, 0.f, 0.f);
    int nfull = (end - beg) & ~3;
    int j = beg;
#pragma unroll 4
    for (; j < beg + nfull; j += 4) {
        int2 e = edges[j + eg];
        float v = __int_as_float(e.y);
        uint2 u = ((const uint2*)(xh + (size_t)e.x * 64))[c];
        float2 f0 = __half22float2(u_as_h2(u.x));
        float2 f1 = __half22float2(u_as_h2(u.y));
        acc.x += v * f0.x; acc.y += v * f0.y; acc.z += v * f1.x; acc.w += v * f1.y;
    }
    if (j + eg < end) {
        int2 e = edges[j + eg];
        float v = __int_as_float(e.y);
        uint2 u = ((const uint2*)(xh + (size_t)e.x * 64))[c];
        float2 f0 = __half22float2(u_as_h2(u.x));
        float2 f1 = __half22float2(u_as_h2(u.y));
        acc.x += v * f0.x; acc.y += v * f0.y; acc.z += v * f1.x; acc.w += v * f1.y;
    }
    acc.x += __shfl_xor(acc.x, 16); acc.y += __shfl_xor(acc.y, 16);
    acc.z += __shfl_xor(acc.z, 16); acc.w += __shfl_xor(acc.w, 16);
    acc.x += __shfl_xor(acc.x, 32); acc.y += __shfl_xor(acc.y, 32);
    acc.z += __shfl_xor(acc.z, 32); acc.w += __shfl_xor(acc.w, 32);
    if (eg == 0) {
        ((float4*)(y + (size_t)wid * 256))[c] = acc;
        uint2 o;
        o.x = h2_as_u(__floats2half2_rn(acc.x, acc.y));
        o.y = h2_as_u(__floats2half2_rn(acc.z, acc.w));
        ((uint2*)(yh + (size_t)wid * 64))[c] = o;
    }
}

// ---------------- fp16-gather SpMM layer-3 + fused 4-layer mean ------------------
__global__ void __launch_bounds__(256) spmm_mean_h_kernel(const int* __restrict__ offs,
                                                          const int2* __restrict__ edges,
                                                          const __half* __restrict__ xh,
                                                          float* __restrict__ y,
                                                          const float4* __restrict__ embs,
                                                          float4* __restrict__ users,
                                                          float4* __restrict__ items,
                                                          int n_users, int n) {
    int wid  = (int)((blockIdx.x * (size_t)blockDim.x + threadIdx.x) >> 6);
    if (wid >= n) return;
    int lane = threadIdx.x & 63;
    int eg   = lane >> 4;
    int c    = lane & 15;
    int beg = offs[wid], end = offs[wid + 1];
    float4 acc = make_float4(0.f, 0.f, 0.f, 0.f);
    int nfull = (end - beg) & ~3;
    int j = beg;
#pragma unroll 4
    for (; j < beg + nfull; j += 4) {
        int2 e = edges[j + eg];
        float v = __int_as_float(e.y);
        uint2 u = ((const uint2*)(xh + (size_t)e.x * 64))[c];
        float2 f0 = __half22float2(u_as_h2(u.x));
        float2 f1 = __half22float2(u_as_h2(u.y));
        acc.x += v * f0.x; acc.y += v * f0.y; acc.z += v * f1.x; acc.w += v * f1.y;
    }
    if (j + eg < end) {
        int2 e = edges[j + eg];
        float v = __int_as_float(e.y);
        uint2 u = ((const uint2*)(xh + (size_t)e.x * 64))[c];
        float2 f0 = __half22float2(u_as_h2(u.x));
        float2 f1 = __half22float2(u_as_h2(u.y));
        acc.x += v * f0.x; acc.y += v * f0.y; acc.z += v * f1.x; acc.w += v * f1.y;
    }
    acc.x += __shfl_xor(acc.x, 16); acc.y += __shfl_xor(acc.y, 16);
    acc.z += __shfl_xor(acc.z, 16); acc.w += __shfl_xor(acc.w, 16);
    acc.x += __shfl_xor(acc.x, 32); acc.y += __shfl_xor(acc.y, 32);
    acc.z += __shfl_xor(acc.z, 32); acc.w += __shfl_xor(acc.w, 32);
    if (eg == 0) {
        ((float4*)(y + (size_t)wid * 256))[c] = acc;
        const float4* p = embs + (size_t)wid * 64 + c;
        float4 a = p[0], b = p[16], d = p[32];
        float4 mv;
        mv.x = (a.x + b.x + d.x + acc.x) * 0.25f;
        mv.y = (a.y + b.y + d.y + acc.y) * 0.25f;
        mv.z = (a.z + b.z + d.z + acc.z) * 0.25f;
        mv.w = (a.w + b.w + d.w + acc.w) * 0.25f;
        if (wid < n_users) users[wid * 16 + c] = mv;
        else               items[(wid - n_users) * 16 + c] = mv;
    }
}

// ---------------- fp32 SpMM fallback (ws too small for fp16 copies) --------------
__global__ void __launch_bounds__(256) spmm_kernel(const int* __restrict__ offs,
                                                   const int2* __restrict__ edges,
                                                   const float* __restrict__ x,
                                                   float* __restrict__ y, int n) {
    int wid  = (int)((blockIdx.x * (size_t)blockDim.x + threadIdx.x) >> 6);
    if (wid >= n) return;
    int lane = threadIdx.x & 63;
    int eg   = lane >> 4;
    int c    = lane & 15;
    int beg = offs[wid], end = offs[wid + 1];
    float4 acc = make_float4(0.f, 0.f, 0.f, 0.f);
    int nfull = (end - beg) & ~3;
    int j = beg;
#pragma unroll 4
    for (; j < beg + nfull; j += 4) {
        int2 e = edges[j + eg];
        float v = __int_as_float(e.y);
        float4 xv = ((const float4*)(x + (size_t)e.x * 256))[c];
        acc.x += v * xv.x; acc.y += v * xv.y; acc.z += v * xv.z; acc.w += v * xv.w;
    }
    if (j + eg < end) {
        int2 e = edges[j + eg];
        float v = __int_as_float(e.y);
        float4 xv = ((const float4*)(x + (size_t)e.x * 256))[c];
        acc.x += v * xv.x; acc.y += v * xv.y; acc.z += v * xv.z; acc.w += v * xv.w;
    }
    acc.x += __shfl_xor(acc.x, 16); acc.y += __shfl_xor(acc.y, 16);
    acc.z += __shfl_xor(acc.z, 16); acc.w += __shfl_xor(acc.w, 16);
    acc.x += __shfl_xor(acc.x, 32); acc.y += __shfl_xor(acc.y, 32);
    acc.z += __shfl_xor(acc.z, 32); acc.w += __shfl_xor(acc.w, 32);
    if (eg == 0)
        ((float4*)(y + (size_t)wid * 256))[c] = acc;
}

__global__ void __launch_bounds__(256) spmm_mean_kernel(const int* __restrict__ offs,
                                                        const int2* __restrict__ edges,
                                                        const float* __restrict__ x,
                                                        float* __restrict__ y,
                                                        const float4* __restrict__ embs,
                                                        float4* __restrict__ users,
                                                        float4* __restrict__ items,
                                                        int n_users, int n) {
    int wid  = (int)((blockIdx.x * (size_t)blockDim.x + threadIdx.x) >> 6);
    if (wid >= n) return;
    int lane = threadIdx.x & 63;
    int eg   = lane >> 4;
    int c    = lane & 15;
    int beg = offs[wid], end = offs[wid + 1];
    float4 acc = make_float4(0.f, 0.f, 0.f, 0.f);
    int nfull = (end - beg) & ~3;
    int j = beg;
#pragma unroll 4
    for (; j < beg + nfull; j += 4) {
        int2 e = edges[j + eg];
        float v = __int_as_float(e.y);
        float4 xv = ((const float4*)(x + (size_t)e.x * 256))[c];
        acc.x += v * xv.x; acc.y += v * xv.y; acc.z += v * xv.z; acc.w += v * xv.w;
    }
    if (j + eg < end) {
        int2 e = edges[j + eg];
        float v = __int_as_float(e.y);
        float4 xv = ((const float4*)(x + (size_t)e.x * 256))[c];
        acc.x += v * xv.x; acc.y += v * xv.y; acc.z += v * xv.z; acc.w += v * xv.w;
    }
    acc.x += __shfl_xor(acc.x, 16); acc.y += __shfl_xor(acc.y, 16);
    acc.z += __shfl_xor(acc.z, 16); acc.w += __shfl_xor(acc.w, 16);
    acc.x += __shfl_xor(acc.x, 32); acc.y += __shfl_xor(acc.y, 32);
    acc.z += __shfl_xor(acc.z, 32); acc.w += __shfl_xor(acc.w, 32);
    if (eg == 0) {
        ((float4*)(y + (size_t)wid * 256))[c] = acc;
        const float4* p = embs + (size_t)wid * 64 + c;
        float4 a = p[0], b = p[16], d = p[32];
        float4 mv;
        mv.x = (a.x + b.x + d.x + acc.x) * 0.25f;
        mv.y = (a.y + b.y + d.y + acc.y) * 0.25f;
        mv.z = (a.z + b.z + d.z + acc.z) * 0.25f;
        mv.w = (a.w + b.w + d.w + acc.w) * 0.25f;
        if (wid < n_users) users[wid * 16 + c] = mv;
        else               items[(wid - n_users) * 16 + c] = mv;
    }
}

extern "C" void kernel_launch(void* const* d_in, const int* in_sizes, int n_in,
                              void* d_out, int out_size, void* d_ws, size_t ws_size,
                              hipStream_t stream) {
    const float* user_emb = (const float*)d_in[0];
    const float* item_emb = (const float*)d_in[1];
    const int*   edge_row = (const int*)d_in[2];
    const int*   edge_col = (const int*)d_in[3];
    const float* edge_val = (const float*)d_in[4];

    const int n_users = in_sizes[0] / D;
    const int n_items = in_sizes[1] / D;
    const int n       = n_users + n_items;
    const int m       = in_sizes[2];

    float* out_users = (float*)d_out;                       // (n_users, 64)
    float* out_items = out_users + (size_t)n_users * D;     // (n_items, 64)
    float* embs      = out_items + (size_t)n_items * D;     // (n, 4, 64)

    const int nb = (n + 255) / 256;                         // 586 scan blocks (<=1024)

    // workspace carve: cedges + fp16 ping-pong + CSR scan scratch
    const size_t xh_bytes = (size_t)n * 128;                // 64 halves/row
    char* ws = (char*)d_ws;
    size_t off = 0;
    int2*   cedges = (int2*)(ws + off);  off += (size_t)m * sizeof(int2);
    __half* xh_a   = (__half*)(ws + off); off += xh_bytes;
    __half* xh_b   = (__half*)(ws + off); off += xh_bytes;
    int*    offs   = (int*)(ws + off);   off += (size_t)(n + 1) * sizeof(int);
    int*    cursors= (int*)(ws + off);   off += (size_t)n * sizeof(int);
    int*    bsum   = (int*)(ws + off);   off += (size_t)nb * sizeof(int);
    int*    boff   = (int*)(ws + off);   off += (size_t)nb * sizeof(int);
    bool fp16path = (ws_size >= off) && (nb <= 1024);

    if (!fp16path) {
        // fp32 fallback carve (no fp16 copies)
        off = 0;
        cedges = (int2*)(ws + off);  off += (size_t)m * sizeof(int2);
        offs   = (int*)(ws + off);   off += (size_t)(n + 1) * sizeof(int);
        cursors= (int*)(ws + off);   off += (size_t)n * sizeof(int);
        bsum   = (int*)(ws + off);   off += (size_t)nb * sizeof(int);
        boff   = (int*)(ws + off);   off += (size_t)nb * sizeof(int);
    }

    // ---- CSR build: hist -> hierarchical scan -> single scattered placement ----
    hipMemsetAsync(offs, 0, (size_t)n * sizeof(int), stream);
    hist_kernel<<<(m + 255) / 256, 256, 0, stream>>>(edge_row, offs, m);
    blocksum_kernel<<<nb, 256, 0, stream>>>(offs, bsum, n);
    scanb_kernel<<<1, 1024, 0, stream>>>(bsum, boff, nb);
    final_kernel<<<nb, 256, 0, stream>>>(offs, cursors, boff, n, m);
    scatter_kernel<<<(m + 255) / 256, 256, 0, stream>>>(
        edge_row, edge_col, edge_val, cursors, cedges, m);

    // ---- layer-0 embeddings (+ fp16 copy when enabled) ----
    init_emb_kernel<<<(n * 16 + 255) / 256, 256, 0, stream>>>(
        (const float4*)user_emb, (const float4*)item_emb, (float4*)embs,
        fp16path ? xh_a : (__half*)nullptr, n_users, n);

    // ---- three propagation layers ----
    if (fp16path) {
        spmm_h_kernel<<<(n + 3) / 4, 256, 0, stream>>>(offs, cedges, xh_a,
                                                       embs + (size_t)1 * D, xh_b, n);
        spmm_h_kernel<<<(n + 3) / 4, 256, 0, stream>>>(offs, cedges, xh_b,
                                                       embs + (size_t)2 * D, xh_a, n);
        spmm_mean_h_kernel<<<(n + 3) / 4, 256, 0, stream>>>(offs, cedges, xh_a,
                                                            embs + (size_t)3 * D,
                                                            (const float4*)embs,
                                                            (float4*)out_users,
                                                            (float4*)out_items,
                                                            n_users, n);
    } else {
        spmm_kernel<<<(n + 3) / 4, 256, 0, stream>>>(offs, cedges,
                                                     embs + (size_t)0 * D,
                                                     embs + (size_t)1 * D, n);
        spmm_kernel<<<(n + 3) / 4, 256, 0, stream>>>(offs, cedges,
                                                     embs + (size_t)1 * D,
                                                     embs + (size_t)2 * D, n);
        spmm_mean_kernel<<<(n + 3) / 4, 256, 0, stream>>>(offs, cedges,
                                                          embs + (size_t)2 * D,
                                                          embs + (size_t)3 * D,
                                                          (const float4*)embs,
                                                          (float4*)out_users,
                                                          (float4*)out_items,
                                                          n_users, n);
    }
}

// Round 8
// 538.566 us; speedup vs baseline: 1.5138x; 1.5138x over previous
//
#include <hip/hip_runtime.h>
#include <hip/hip_fp16.h>

#define D 64
#define TILE 4096          // edges per radix tile (256 threads x 16)
#define BKSHIFT 9          // rows per coarse bucket = 512
#define NBKMAX 512         // max coarse buckets (scan handles exactly 512)
#define COLBITS 18         // col fits in 18 bits (n <= 262144); row-low packed above
#define COLMASK ((1 << COLBITS) - 1)
#define SCHUNK 2048        // elements per block in the hierarchical hm-scan

__device__ __forceinline__ unsigned h2_as_u(__half2 h) { return *reinterpret_cast<unsigned*>(&h); }
__device__ __forceinline__ __half2 u_as_h2(unsigned u) { return *reinterpret_cast<__half2*>(&u); }

// ---------------- layer-0 init: embs[node][0][:] = concat(user_emb, item_emb) ----
// Also emits the fp16 gather copy (xh) when enabled.
__global__ void init_emb_kernel(const float4* __restrict__ ue, const float4* __restrict__ ie,
                                float4* __restrict__ embs, __half* __restrict__ xh,
                                int n_users, int n) {
    int idx  = blockIdx.x * blockDim.x + threadIdx.x;     // over n*16 float4s
    int node = idx >> 4, q = idx & 15;
    if (node >= n) return;
    float4 v = (node < n_users) ? ue[node * 16 + q] : ie[(node - n_users) * 16 + q];
    embs[(size_t)node * 64 + q] = v;                      // node stride = 256 floats = 64 float4
    if (xh) {
        uint2 o;
        o.x = h2_as_u(__floats2half2_rn(v.x, v.y));
        o.y = h2_as_u(__floats2half2_rn(v.z, v.w));
        ((uint2*)(xh + (size_t)node * 64))[q] = o;        // 128B fp16 row
    }
}

// ================= radix CSR build (no global atomics) ===========================
// passA: per-tile histogram over coarse buckets -> hm[b*ntiles + t]
__global__ void passA_kernel(const int* __restrict__ row, int* __restrict__ hm,
                             int m, int ntiles, int nbk) {
    __shared__ int h[NBKMAX];
    int t = threadIdx.x;
    for (int b = t; b < nbk; b += 256) h[b] = 0;
    __syncthreads();
    int base = blockIdx.x * TILE;
    for (int k = 0; k < TILE; k += 256) {
        int i = base + k + t;
        if (i < m) atomicAdd(&h[row[i] >> BKSHIFT], 1);
    }
    __syncthreads();
    for (int b = t; b < nbk; b += 256) hm[b * ntiles + blockIdx.x] = h[b];
}

// ---- hierarchical scan of hm (bucket-major) -> absolute edge offsets ----
__global__ void passB1_kernel(const int* __restrict__ hm, int* __restrict__ bsums, int len) {
    __shared__ int s[256];
    int t = threadIdx.x;
    int base = blockIdx.x * SCHUNK;
    int sum = 0;
#pragma unroll
    for (int k = 0; k < SCHUNK; k += 256) {
        int i = base + k + t;
        if (i < len) sum += hm[i];
    }
    s[t] = sum;
    __syncthreads();
    for (int d = 128; d > 0; d >>= 1) {
        if (t < d) s[t] += s[t + d];
        __syncthreads();
    }
    if (t == 0) bsums[blockIdx.x] = s[0];
}

__global__ void __launch_bounds__(1024) passB2_kernel(int* __restrict__ bsums,
                                                      int* __restrict__ bstart,
                                                      int* __restrict__ offs_n,
                                                      int nblk, int total, int nbk) {
    __shared__ int s[1024];
    int t = threadIdx.x;
    int v = (t < nblk) ? bsums[t] : 0;
    s[t] = v;
    for (int d = 1; d < 1024; d <<= 1) {
        __syncthreads();
        int add = (t >= d) ? s[t - d] : 0;
        __syncthreads();
        s[t] += add;
    }
    __syncthreads();
    if (t < nblk) bsums[t] = s[t] - v;           // exclusive block offset
    if (t == 0) { bstart[nbk] = total; offs_n[0] = total; }
}

__global__ void passB3_kernel(int* __restrict__ hm, const int* __restrict__ bsums,
                              int* __restrict__ bstart, int len, int ntiles) {
    __shared__ int s[SCHUNK];
    __shared__ int ts[256];
    int t = threadIdx.x;
    int base = blockIdx.x * SCHUNK;
#pragma unroll
    for (int k = 0; k < SCHUNK; k += 256) {       // coalesced load
        int i = base + k + t;
        s[k + t] = (i < len) ? hm[i] : 0;
    }
    __syncthreads();
    const int PT = SCHUNK / 256;                  // 8 contiguous elems per thread
    int o = t * PT;
    int sum = 0;
#pragma unroll
    for (int k = 0; k < PT; ++k) sum += s[o + k];
    ts[t] = sum;
    for (int d = 1; d < 256; d <<= 1) {
        __syncthreads();
        int add = (t >= d) ? ts[t - d] : 0;
        __syncthreads();
        ts[t] += add;
    }
    __syncthreads();
    int run = bsums[blockIdx.x] + ts[t] - sum;    // exclusive prefix at s[o]
#pragma unroll
    for (int k = 0; k < PT; ++k) {
        int v = s[o + k];
        s[o + k] = run;
        run += v;
    }
    __syncthreads();
#pragma unroll
    for (int k = 0; k < SCHUNK; k += 256) {       // coalesced store
        int i = base + k + t;
        if (i < len) {
            int pv = s[k + t];
            hm[i] = pv;
            if (i % ntiles == 0) bstart[i / ntiles] = pv;
        }
    }
}

// legacy single-block scan (only if nblk > 1024 — never at this problem size)
__global__ void __launch_bounds__(1024) passB_kernel(int* __restrict__ hm,
                                                     int* __restrict__ bstart,
                                                     int* __restrict__ offs_n,
                                                     int total, int len, int ntiles, int nbk) {
    __shared__ int s[1024];
    int t = threadIdx.x;
    int chunk = (len + 1023) / 1024;
    int beg = t * chunk;
    int end = beg + chunk; if (end > len) end = len; if (beg > len) beg = len;
    int sum = 0;
    for (int i = beg; i < end; ++i) sum += hm[i];
    s[t] = sum;
    for (int d = 1; d < 1024; d <<= 1) {
        __syncthreads();
        int add = (t >= d) ? s[t - d] : 0;
        __syncthreads();
        s[t] += add;
    }
    __syncthreads();
    int run = s[t] - sum;
    for (int i = beg; i < end; ++i) {
        int v = hm[i];
        hm[i] = run;
        if (i % ntiles == 0) bstart[i / ntiles] = run;
        run += v;
    }
    if (t == 0) { bstart[nbk] = total; offs_n[0] = total; }
}

// passC v2: block-local counting sort into LDS staging, then COALESCED write-out.
// Eliminates partial-line RMW on bcv (R7 evidence: 8B scatter = 7.7x write
// amplification). Each (tile,bucket) run is contiguous in LDS and in bcv, and
// the write-out loop has consecutive threads writing consecutive addresses.
__global__ void __launch_bounds__(256) passC_kernel(const int* __restrict__ row,
                                                    const int* __restrict__ col,
                                                    const float* __restrict__ val,
                                                    const int* __restrict__ hm,
                                                    int2* __restrict__ bcv,
                                                    int m, int ntiles, int nbk) {
    __shared__ int  lh[NBKMAX];        // local bucket counts -> rank cursors
    __shared__ int  lscan[NBKMAX];     // exclusive scan of local counts
    __shared__ int  gbase[NBKMAX];     // global run base = hm[b*ntiles + tile]
    __shared__ int  ts[256];           // scan scratch
    __shared__ int2 se[TILE];          // staged edges (32 KB)
    __shared__ unsigned short sbk[TILE]; // bucket id per slot (8 KB)
    int t = threadIdx.x;
    int tile = blockIdx.x;
    for (int b = t; b < NBKMAX; b += 256) lh[b] = 0;
    for (int b = t; b < nbk; b += 256) gbase[b] = hm[b * ntiles + tile];
    __syncthreads();
    int base = tile * TILE;
    int cnt  = m - base; if (cnt > TILE) cnt = TILE;
    int ecol[16], eval_[16], erank[16], ebkt[16];
#pragma unroll
    for (int k = 0; k < 16; ++k) {
        int i = base + k * 256 + t;
        ebkt[k] = -1;
        if (i < m) {
            int r = row[i];
            int b = r >> BKSHIFT;
            ecol[k]  = col[i] | ((r & ((1 << BKSHIFT) - 1)) << COLBITS);
            eval_[k] = __float_as_int(val[i]);
            erank[k] = atomicAdd(&lh[b], 1);
            ebkt[k]  = b;
        }
    }
    __syncthreads();
    // exclusive scan of lh[0..512) with 256 threads (2 entries/thread)
    int a0 = lh[2 * t], a1 = lh[2 * t + 1];
    int s2 = a0 + a1;
    ts[t] = s2;
    for (int d = 1; d < 256; d <<= 1) {
        __syncthreads();
        int add = (t >= d) ? ts[t - d] : 0;
        __syncthreads();
        ts[t] += add;
    }
    __syncthreads();
    int ebase = ts[t] - s2;
    lscan[2 * t]     = ebase;
    lscan[2 * t + 1] = ebase + a0;
    __syncthreads();
#pragma unroll
    for (int k = 0; k < 16; ++k) {
        if (ebkt[k] >= 0) {
            int slot = lscan[ebkt[k]] + erank[k];
            se[slot]  = make_int2(ecol[k], eval_[k]);
            sbk[slot] = (unsigned short)ebkt[k];
        }
    }
    __syncthreads();
    for (int p = t; p < cnt; p += 256) {          // coalesced streaming write-out
        int b = sbk[p];
        bcv[gbase[b] + (p - lscan[b])] = se[p];
    }
}

// pass2: one block per bucket (512 rows). LDS row-hist + scan -> row CSR offs,
// then exact placement; all scattered writes stay in this bucket's segment.
__global__ void __launch_bounds__(512) pass2_kernel(const int2* __restrict__ bcv,
                                                    const int* __restrict__ bstart,
                                                    int* __restrict__ offs,
                                                    int2* __restrict__ cedges, int n) {
    __shared__ int hist[1 << BKSHIFT];
    __shared__ int s[1 << BKSHIFT];
    int b = blockIdx.x;
    int t = threadIdx.x;
    int e0 = bstart[b], e1 = bstart[b + 1];
    hist[t] = 0;
    __syncthreads();
    for (int i = e0 + t; i < e1; i += 512)
        atomicAdd(&hist[((unsigned)bcv[i].x) >> COLBITS], 1);
    __syncthreads();
    int v = hist[t];
    s[t] = v;
    for (int d = 1; d < 512; d <<= 1) {
        __syncthreads();
        int add = (t >= d) ? s[t - d] : 0;
        __syncthreads();
        s[t] += add;
    }
    __syncthreads();
    int abs_off = e0 + s[t] - v;           // absolute CSR start of this row
    int grow = (b << BKSHIFT) + t;
    if (grow < n) offs[grow] = abs_off;
    __syncthreads();
    hist[t] = abs_off;                     // reuse as absolute cursor
    __syncthreads();
    for (int i = e0 + t; i < e1; i += 512) {
        int2 e = bcv[i];
        unsigned u = (unsigned)e.x;
        int pos = atomicAdd(&hist[u >> COLBITS], 1);
        cedges[pos] = make_int2((int)(u & COLMASK), e.y);
    }
}

// ================= legacy fallback (ws too small / n too big) ====================
__global__ void hist_kernel(const int* __restrict__ row, int* __restrict__ counts, int m) {
    int i = blockIdx.x * blockDim.x + threadIdx.x;
    if (i < m) atomicAdd(&counts[row[i]], 1);
}
__global__ void blocksum_kernel(const int* __restrict__ counts, int* __restrict__ bsum, int n) {
    __shared__ int s[256];
    int t = threadIdx.x;
    int i = blockIdx.x * 256 + t;
    s[t] = (i < n) ? counts[i] : 0;
    __syncthreads();
    for (int d = 128; d > 0; d >>= 1) {
        if (t < d) s[t] += s[t + d];
        __syncthreads();
    }
    if (t == 0) bsum[blockIdx.x] = s[0];
}
__global__ void scanb_kernel(const int* __restrict__ bsum, int* __restrict__ boff, int nb) {
    __shared__ int s[1024];
    int t = threadIdx.x;
    int v = (t < nb) ? bsum[t] : 0;
    s[t] = v;
    for (int d = 1; d < 1024; d <<= 1) {
        __syncthreads();
        int add = (t >= d) ? s[t - d] : 0;
        __syncthreads();
        s[t] += add;
    }
    __syncthreads();
    if (t < nb) boff[t] = s[t] - v;
}
__global__ void final_kernel(int* __restrict__ offs, int* __restrict__ cursors,
                             const int* __restrict__ boff, int n, int total) {
    __shared__ int s[256];
    int t = threadIdx.x;
    int i = blockIdx.x * 256 + t;
    int v = (i < n) ? offs[i] : 0;
    s[t] = v;
    for (int d = 1; d < 256; d <<= 1) {
        __syncthreads();
        int add = (t >= d) ? s[t - d] : 0;
        __syncthreads();
        s[t] += add;
    }
    __syncthreads();
    int excl = s[t] - v + boff[blockIdx.x];
    if (i < n) { offs[i] = excl; cursors[i] = excl; }
    if (i == 0) offs[n] = total;
}
__global__ void scatter_kernel(const int* __restrict__ row, const int* __restrict__ col,
                               const float* __restrict__ val, int* __restrict__ cursors,
                               int2* __restrict__ edges, int m) {
    int i = blockIdx.x * blockDim.x + threadIdx.x;
    if (i >= m) return;
    int r   = row[i];
    int pos = atomicAdd(&cursors[r], 1);
    edges[pos] = make_int2(col[i], __float_as_int(val[i]));
}

// ---------------- fp16-gather SpMM: one wave per row, 4 edges in flight ----------
__global__ void __launch_bounds__(256) spmm_h_kernel(const int* __restrict__ offs,
                                                     const int2* __restrict__ edges,
                                                     const __half* __restrict__ xh,
                                                     float* __restrict__ y,
                                                     __half* __restrict__ yh, int n) {
    int wid  = (int)((blockIdx.x * (size_t)blockDim.x + threadIdx.x) >> 6);
    if (wid >= n) return;
    int lane = threadIdx.x & 63;
    int eg   = lane >> 4;      // which of 4 concurrent edges
    int c    = lane & 15;      // 4-dim chunk within the 64-dim row
    int beg = offs[wid], end = offs[wid + 1];
    float4 acc = make_float4(0.f, 0.f, 0.f, 0.f);
    int nfull = (end - beg) & ~3;
    int j = beg;
#pragma unroll 4
    for (; j < beg + nfull; j += 4) {
        int2 e = edges[j + eg];
        float v = __int_as_float(e.y);
        uint2 u = ((const uint2*)(xh + (size_t)e.x * 64))[c];
        float2 f0 = __half22float2(u_as_h2(u.x));
        float2 f1 = __half22float2(u_as_h2(u.y));
        acc.x += v * f0.x; acc.y += v * f0.y; acc.z += v * f1.x; acc.w += v * f1.y;
    }
    if (j + eg < end) {
        int2 e = edges[j + eg];
        float v = __int_as_float(e.y);
        uint2 u = ((const uint2*)(xh + (size_t)e.x * 64))[c];
        float2 f0 = __half22float2(u_as_h2(u.x));
        float2 f1 = __half22float2(u_as_h2(u.y));
        acc.x += v * f0.x; acc.y += v * f0.y; acc.z += v * f1.x; acc.w += v * f1.y;
    }
    acc.x += __shfl_xor(acc.x, 16); acc.y += __shfl_xor(acc.y, 16);
    acc.z += __shfl_xor(acc.z, 16); acc.w += __shfl_xor(acc.w, 16);
    acc.x += __shfl_xor(acc.x, 32); acc.y += __shfl_xor(acc.y, 32);
    acc.z += __shfl_xor(acc.z, 32); acc.w += __shfl_xor(acc.w, 32);
    if (eg == 0) {
        ((float4*)(y + (size_t)wid * 256))[c] = acc;
        uint2 o;
        o.x = h2_as_u(__floats2half2_rn(acc.x, acc.y));
        o.y = h2_as_u(__floats2half2_rn(acc.z, acc.w));
        ((uint2*)(yh + (size_t)wid * 64))[c] = o;
    }
}

// ---------------- fp16-gather SpMM layer-3 + fused 4-layer mean ------------------
__global__ void __launch_bounds__(256) spmm_mean_h_kernel(const int* __restrict__ offs,
                                                          const int2* __restrict__ edges,
                                                          const __half* __restrict__ xh,
                                                          float* __restrict__ y,
                                                          const float4* __restrict__ embs,
                                                          float4* __restrict__ users,
                                                          float4* __restrict__ items,
                                                          int n_users, int n) {
    int wid  = (int)((blockIdx.x * (size_t)blockDim.x + threadIdx.x) >> 6);
    if (wid >= n) return;
    int lane = threadIdx.x & 63;
    int eg   = lane >> 4;
    int c    = lane & 15;
    int beg = offs[wid], end = offs[wid + 1];
    float4 acc = make_float4(0.f, 0.f, 0.f, 0.f);
    int nfull = (end - beg) & ~3;
    int j = beg;
#pragma unroll 4
    for (; j < beg + nfull; j += 4) {
        int2 e = edges[j + eg];
        float v = __int_as_float(e.y);
        uint2 u = ((const uint2*)(xh + (size_t)e.x * 64))[c];
        float2 f0 = __half22float2(u_as_h2(u.x));
        float2 f1 = __half22float2(u_as_h2(u.y));
        acc.x += v * f0.x; acc.y += v * f0.y; acc.z += v * f1.x; acc.w += v * f1.y;
    }
    if (j + eg < end) {
        int2 e = edges[j + eg];
        float v = __int_as_float(e.y);
        uint2 u = ((const uint2*)(xh + (size_t)e.x * 64))[c];
        float2 f0 = __half22float2(u_as_h2(u.x));
        float2 f1 = __half22float2(u_as_h2(u.y));
        acc.x += v * f0.x; acc.y += v * f0.y; acc.z += v * f1.x; acc.w += v * f1.y;
    }
    acc.x += __shfl_xor(acc.x, 16); acc.y += __shfl_xor(acc.y, 16);
    acc.z += __shfl_xor(acc.z, 16); acc.w += __shfl_xor(acc.w, 16);
    acc.x += __shfl_xor(acc.x, 32); acc.y += __shfl_xor(acc.y, 32);
    acc.z += __shfl_xor(acc.z, 32); acc.w += __shfl_xor(acc.w, 32);
    if (eg == 0) {
        ((float4*)(y + (size_t)wid * 256))[c] = acc;
        const float4* p = embs + (size_t)wid * 64 + c;
        float4 a = p[0], b = p[16], d = p[32];
        float4 mv;
        mv.x = (a.x + b.x + d.x + acc.x) * 0.25f;
        mv.y = (a.y + b.y + d.y + acc.y) * 0.25f;
        mv.z = (a.z + b.z + d.z + acc.z) * 0.25f;
        mv.w = (a.w + b.w + d.w + acc.w) * 0.25f;
        if (wid < n_users) users[wid * 16 + c] = mv;
        else               items[(wid - n_users) * 16 + c] = mv;
    }
}

// ---------------- fp32 SpMM fallback (ws too small for fp16 copies) --------------
__global__ void __launch_bounds__(256) spmm_kernel(const int* __restrict__ offs,
                                                   const int2* __restrict__ edges,
                                                   const float* __restrict__ x,
                                                   float* __restrict__ y, int n) {
    int wid  = (int)((blockIdx.x * (size_t)blockDim.x + threadIdx.x) >> 6);
    if (wid >= n) return;
    int lane = threadIdx.x & 63;
    int eg   = lane >> 4;
    int c    = lane & 15;
    int beg = offs[wid], end = offs[wid + 1];
    float4 acc = make_float4(0.f, 0.f, 0.f, 0.f);
    int nfull = (end - beg) & ~3;
    int j = beg;
#pragma unroll 4
    for (; j < beg + nfull; j += 4) {
        int2 e = edges[j + eg];
        float v = __int_as_float(e.y);
        float4 xv = ((const float4*)(x + (size_t)e.x * 256))[c];
        acc.x += v * xv.x; acc.y += v * xv.y; acc.z += v * xv.z; acc.w += v * xv.w;
    }
    if (j + eg < end) {
        int2 e = edges[j + eg];
        float v = __int_as_float(e.y);
        float4 xv = ((const float4*)(x + (size_t)e.x * 256))[c];
        acc.x += v * xv.x; acc.y += v * xv.y; acc.z += v * xv.z; acc.w += v * xv.w;
    }
    acc.x += __shfl_xor(acc.x, 16); acc.y += __shfl_xor(acc.y, 16);
    acc.z += __shfl_xor(acc.z, 16); acc.w += __shfl_xor(acc.w, 16);
    acc.x += __shfl_xor(acc.x, 32); acc.y += __shfl_xor(acc.y, 32);
    acc.z += __shfl_xor(acc.z, 32); acc.w += __shfl_xor(acc.w, 32);
    if (eg == 0)
        ((float4*)(y + (size_t)wid * 256))[c] = acc;
}

__global__ void __launch_bounds__(256) spmm_mean_kernel(const int* __restrict__ offs,
                                                        const int2* __restrict__ edges,
                                                        const float* __restrict__ x,
                                                        float* __restrict__ y,
                                                        const float4* __restrict__ embs,
                                                        float4* __restrict__ users,
                                                        float4* __restrict__ items,
                                                        int n_users, int n) {
    int wid  = (int)((blockIdx.x * (size_t)blockDim.x + threadIdx.x) >> 6);
    if (wid >= n) return;
    int lane = threadIdx.x & 63;
    int eg   = lane >> 4;
    int c    = lane & 15;
    int beg = offs[wid], end = offs[wid + 1];
    float4 acc = make_float4(0.f, 0.f, 0.f, 0.f);
    int nfull = (end - beg) & ~3;
    int j = beg;
#pragma unroll 4
    for (; j < beg + nfull; j += 4) {
        int2 e = edges[j + eg];
        float v = __int_as_float(e.y);
        float4 xv = ((const float4*)(x + (size_t)e.x * 256))[c];
        acc.x += v * xv.x; acc.y += v * xv.y; acc.z += v * xv.z; acc.w += v * xv.w;
    }
    if (j + eg < end) {
        int2 e = edges[j + eg];
        float v = __int_as_float(e.y);
        float4 xv = ((const float4*)(x + (size_t)e.x * 256))[c];
        acc.x += v * xv.x; acc.y += v * xv.y; acc.z += v * xv.z; acc.w += v * xv.w;
    }
    acc.x += __shfl_xor(acc.x, 16); acc.y += __shfl_xor(acc.y, 16);
    acc.z += __shfl_xor(acc.z, 16); acc.w += __shfl_xor(acc.w, 16);
    acc.x += __shfl_xor(acc.x, 32); acc.y += __shfl_xor(acc.y, 32);
    acc.z += __shfl_xor(acc.z, 32); acc.w += __shfl_xor(acc.w, 32);
    if (eg == 0) {
        ((float4*)(y + (size_t)wid * 256))[c] = acc;
        const float4* p = embs + (size_t)wid * 64 + c;
        float4 a = p[0], b = p[16], d = p[32];
        float4 mv;
        mv.x = (a.x + b.x + d.x + acc.x) * 0.25f;
        mv.y = (a.y + b.y + d.y + acc.y) * 0.25f;
        mv.z = (a.z + b.z + d.z + acc.z) * 0.25f;
        mv.w = (a.w + b.w + d.w + acc.w) * 0.25f;
        if (wid < n_users) users[wid * 16 + c] = mv;
        else               items[(wid - n_users) * 16 + c] = mv;
    }
}

extern "C" void kernel_launch(void* const* d_in, const int* in_sizes, int n_in,
                              void* d_out, int out_size, void* d_ws, size_t ws_size,
                              hipStream_t stream) {
    const float* user_emb = (const float*)d_in[0];
    const float* item_emb = (const float*)d_in[1];
    const int*   edge_row = (const int*)d_in[2];
    const int*   edge_col = (const int*)d_in[3];
    const float* edge_val = (const float*)d_in[4];

    const int n_users = in_sizes[0] / D;
    const int n_items = in_sizes[1] / D;
    const int n       = n_users + n_items;
    const int m       = in_sizes[2];

    float* out_users = (float*)d_out;                       // (n_users, 64)
    float* out_items = out_users + (size_t)n_users * D;     // (n_items, 64)
    float* embs      = out_items + (size_t)n_items * D;     // (n, 4, 64)

    const int ntiles = (m + TILE - 1) / TILE;               // 733
    const int nbk    = (n + (1 << BKSHIFT) - 1) >> BKSHIFT; // 293 (must be <= NBKMAX)
    const int nb     = (n + 255) / 256;                     // 586 (fallback scan)
    const int len    = nbk * ntiles;                        // ~214,769
    const int nblk   = (len + SCHUNK - 1) / SCHUNK;         // ~105 scan blocks

    // workspace carve. Region X time-shares: bcv during [passC,pass2], then the
    // two fp16 gather buffers xh_a/xh_b during [init, end] (bcv is dead by then).
    const size_t xh_bytes = (size_t)n * 128;                // 64 halves/row
    size_t xregion = 2 * xh_bytes;
    if (xregion < (size_t)m * sizeof(int2)) xregion = (size_t)m * sizeof(int2);

    char* ws = (char*)d_ws;
    size_t off = 0;
    int2* cedges = (int2*)(ws + off); off += (size_t)m * sizeof(int2);
    char* X      = ws + off;          off += xregion;
    int*  offs   = (int*)(ws + off);  off += (size_t)(n + 1) * sizeof(int);
    int*  bstart = (int*)(ws + off);  off += (size_t)(nbk + 1) * sizeof(int);
    int*  hm     = (int*)(ws + off);  off += (size_t)nbk * ntiles * sizeof(int);
    int*  cursors= (int*)(ws + off);  off += (size_t)n * sizeof(int);
    int*  bsum   = (int*)(ws + off);  off += (size_t)nb * sizeof(int);
    int*  boff   = (int*)(ws + off);  off += (size_t)nb * sizeof(int);
    bool fp16path = (ws_size >= off);

    if (!fp16path) {
        // re-carve with X = bcv only (fp32 path, R4 behavior)
        off = 0;
        cedges = (int2*)(ws + off); off += (size_t)m * sizeof(int2);
        X      = ws + off;          off += (size_t)m * sizeof(int2);
        offs   = (int*)(ws + off);  off += (size_t)(n + 1) * sizeof(int);
        bstart = (int*)(ws + off);  off += (size_t)(nbk + 1) * sizeof(int);
        hm     = (int*)(ws + off);  off += (size_t)nbk * ntiles * sizeof(int);
        cursors= (int*)(ws + off);  off += (size_t)n * sizeof(int);
        bsum   = (int*)(ws + off);  off += (size_t)nb * sizeof(int);
        boff   = (int*)(ws + off);  off += (size_t)nb * sizeof(int);
    }
    int2*   bcv  = (int2*)X;
    __half* xh_a = (__half*)X;                    // layer0 / layer2 fp16 copy
    __half* xh_b = (__half*)(X + xh_bytes);       // layer1 fp16 copy
    const bool radix = (ws_size >= off) && (n <= (1 << COLBITS)) && (nbk <= NBKMAX);

    // ---- CSR build first (bcv lifetime ends before init writes xh over it) ----
    if (radix) {
        passA_kernel<<<ntiles, 256, 0, stream>>>(edge_row, hm, m, ntiles, nbk);
        if (nblk <= 1024) {
            passB1_kernel<<<nblk, 256, 0, stream>>>(hm, bsum, len);
            passB2_kernel<<<1, 1024, 0, stream>>>(bsum, bstart, offs + n, nblk, m, nbk);
            passB3_kernel<<<nblk, 256, 0, stream>>>(hm, bsum, bstart, len, ntiles);
        } else {
            passB_kernel<<<1, 1024, 0, stream>>>(hm, bstart, offs + n, m,
                                                 len, ntiles, nbk);
        }
        passC_kernel<<<ntiles, 256, 0, stream>>>(edge_row, edge_col, edge_val, hm,
                                                 bcv, m, ntiles, nbk);
        pass2_kernel<<<nbk, 512, 0, stream>>>(bcv, bstart, offs, cedges, n);
    } else {
        hipMemsetAsync(offs, 0, (size_t)n * sizeof(int), stream);
        hist_kernel<<<(m + 255) / 256, 256, 0, stream>>>(edge_row, offs, m);
        blocksum_kernel<<<nb, 256, 0, stream>>>(offs, bsum, n);
        scanb_kernel<<<1, 1024, 0, stream>>>(bsum, boff, nb);
        final_kernel<<<nb, 256, 0, stream>>>(offs, cursors, boff, n, m);
        scatter_kernel<<<(m + 255) / 256, 256, 0, stream>>>(
            edge_row, edge_col, edge_val, cursors, cedges, m);
    }

    // ---- layer-0 embeddings (+ fp16 copy when enabled) ----
    init_emb_kernel<<<(n * 16 + 255) / 256, 256, 0, stream>>>(
        (const float4*)user_emb, (const float4*)item_emb, (float4*)embs,
        fp16path ? xh_a : (__half*)nullptr, n_users, n);

    // ---- three propagation layers ----
    if (fp16path) {
        spmm_h_kernel<<<(n + 3) / 4, 256, 0, stream>>>(offs, cedges, xh_a,
                                                       embs + (size_t)1 * D, xh_b, n);
        spmm_h_kernel<<<(n + 3) / 4, 256, 0, stream>>>(offs, cedges, xh_b,
                                                       embs + (size_t)2 * D, xh_a, n);
        spmm_mean_h_kernel<<<(n + 3) / 4, 256, 0, stream>>>(offs, cedges, xh_a,
                                                            embs + (size_t)3 * D,
                                                            (const float4*)embs,
                                                            (float4*)out_users,
                                                            (float4*)out_items,
                                                            n_users, n);
    } else {
        spmm_kernel<<<(n + 3) / 4, 256, 0, stream>>>(offs, cedges,
                                                     embs + (size_t)0 * D,
                                                     embs + (size_t)1 * D, n);
        spmm_kernel<<<(n + 3) / 4, 256, 0, stream>>>(offs, cedges,
                                                     embs + (size_t)1 * D,
                                                     embs + (size_t)2 * D, n);
        spmm_mean_kernel<<<(n + 3) / 4, 256, 0, stream>>>(offs, cedges,
                                                          embs + (size_t)2 * D,
                                                          embs + (size_t)3 * D,
                                                          (const float4*)embs,
                                                          (float4*)out_users,
                                                          (float4*)out_items,
                                                          n_users, n);
    }
}